// Round 1
// baseline (115.737 us; speedup 1.0000x reference)
//
#include <hip/hip_runtime.h>
#include <math.h>

#define EPS_F 1e-8f
#define NS 10
#define HDIM 256
#define ROWS_PER_BLOCK 4

__device__ __forceinline__ float fast_tanh(float x) {
    // tanh(x) = sign(x) * (1 - e) / (1 + e),  e = exp(-2|x|)  — no overflow
    float s = fabsf(x);
    float e = __expf(-2.0f * s);
    float r = __builtin_amdgcn_rcpf(1.0f + e);
    float th = (1.0f - e) * r;
    return copysignf(th, x);
}

__device__ __forceinline__ float softplus_f(float x) {
    // log(1 + e^x) = max(x,0) + log(1 + e^{-|x|})  — stable
    float e = __expf(-fabsf(x));
    return fmaxf(x, 0.0f) + __logf(1.0f + e);
}

__global__ __launch_bounds__(256) void intensity_loss_kernel(
    const float* __restrict__ duration,   // [B]
    const float* __restrict__ cx,         // [B,H]
    const float* __restrict__ cbarx,      // [B,H]
    const float* __restrict__ deltx,      // [B,H]
    const float* __restrict__ ox,         // [B,H]
    const float* __restrict__ W,          // [H]
    const float* __restrict__ bptr,       // [1]
    const float* __restrict__ u,          // [NS,B]
    float* __restrict__ out,              // [B]
    int B)
{
    const int wave = threadIdx.x >> 6;
    const int lane = threadIdx.x & 63;
    const int row  = blockIdx.x * ROWS_PER_BLOCK + wave;
    if (row >= B) return;

    const size_t base = (size_t)row * HDIM + (size_t)(lane << 2);

    const float4 vcx = *reinterpret_cast<const float4*>(cx    + base);
    const float4 vcb = *reinterpret_cast<const float4*>(cbarx + base);
    const float4 vdl = *reinterpret_cast<const float4*>(deltx + base);
    const float4 vox = *reinterpret_cast<const float4*>(ox    + base);
    const float4 vw  = *reinterpret_cast<const float4*>(W + (lane << 2));

    float cb[4] = {vcb.x, vcb.y, vcb.z, vcb.w};
    float dx[4] = {vcx.x - vcb.x, vcx.y - vcb.y, vcx.z - vcb.z, vcx.w - vcb.w};
    float dl[4] = {vdl.x, vdl.y, vdl.z, vdl.w};
    float o4[4] = {vox.x, vox.y, vox.z, vox.w};
    float w4[4] = {vw.x,  vw.y,  vw.z,  vw.w};

    const float dur = duration[row];

    float tv[NS + 1];
    tv[0] = dur;
#pragma unroll
    for (int s = 0; s < NS; ++s)
        tv[s + 1] = u[(size_t)s * B + row] * dur;

    float acc[NS + 1];
#pragma unroll
    for (int k = 0; k <= NS; ++k) {
        float a = 0.0f;
        const float t = tv[k];
#pragma unroll
        for (int j = 0; j < 4; ++j) {
            float decay = __expf(-dl[j] * t);
            float c_t   = fmaf(dx[j], decay, cb[j]);
            float h_t   = o4[j] * fast_tanh(c_t);
            a = fmaf(h_t, w4[j], a);
        }
        acc[k] = a;
    }

    // butterfly reduce each of the 11 partial dots across the 64-lane wave
#pragma unroll
    for (int k = 0; k <= NS; ++k) {
        float a = acc[k];
#pragma unroll
        for (int off = 32; off > 0; off >>= 1)
            a += __shfl_xor(a, off, 64);
        acc[k] = a;
    }

    if (lane == 0) {
        const float bb = bptr[0];
        float lam0 = softplus_f(acc[0] + bb);
        float nll  = -__logf(lam0 + EPS_F);
        float integ = 0.0f;
#pragma unroll
        for (int s = 1; s <= NS; ++s)
            integ += softplus_f(acc[s] + bb);
        out[row] = nll + integ * (dur * (1.0f / (float)NS));
    }
}

extern "C" void kernel_launch(void* const* d_in, const int* in_sizes, int n_in,
                              void* d_out, int out_size, void* d_ws, size_t ws_size,
                              hipStream_t stream) {
    const float* duration = (const float*)d_in[0];
    const float* cx       = (const float*)d_in[1];
    const float* cbarx    = (const float*)d_in[2];
    const float* deltx    = (const float*)d_in[3];
    const float* ox       = (const float*)d_in[4];
    const float* W        = (const float*)d_in[5];
    const float* b        = (const float*)d_in[6];
    const float* u        = (const float*)d_in[7];
    float* out            = (float*)d_out;

    const int B = in_sizes[0];           // 65536
    const int grid = (B + ROWS_PER_BLOCK - 1) / ROWS_PER_BLOCK;

    intensity_loss_kernel<<<grid, 256, 0, stream>>>(
        duration, cx, cbarx, deltx, ox, W, b, u, out, B);
}

// Round 2
// 95.457 us; speedup vs baseline: 1.2125x; 1.2125x over previous
//
#include <hip/hip_runtime.h>
#include <math.h>

#define EPS_F 1e-8f
#define NS 10
#define NK 11
#define HDIM 256
#define ROWS_PER_BLOCK 4

__device__ __forceinline__ float softplus_f(float x) {
    // log(1 + e^x) = max(x,0) + log(1 + e^{-|x|})  — stable
    float e = __expf(-fabsf(x));
    return fmaxf(x, 0.0f) + __logf(1.0f + e);
}

// tanh via [5/4] Pade on clamped input: x(945+105y+y^2)/(945+420y+15y^2), y=x^2
// clamped to |x|<=3.5 ; max abs error ~1.1e-3 (boundary), ~3e-4 typical.
__device__ __forceinline__ float pade_tanh(float x) {
    float xc = fminf(3.5f, fmaxf(-3.5f, x));   // -> v_med3_f32
    float y  = xc * xc;
    float num = fmaf(y, fmaf(y, 1.0582011e-3f, 1.1111111e-1f), 1.0f);
    float den = fmaf(y, fmaf(y, 1.5873016e-2f, 4.4444445e-1f), 1.0f);
    return (xc * num) * __builtin_amdgcn_rcpf(den);
}

__global__ __launch_bounds__(256) void intensity_loss_kernel(
    const float* __restrict__ duration,   // [B]
    const float* __restrict__ cx,         // [B,H]
    const float* __restrict__ cbarx,      // [B,H]
    const float* __restrict__ deltx,      // [B,H]
    const float* __restrict__ ox,         // [B,H]
    const float* __restrict__ W,          // [H]
    const float* __restrict__ bptr,       // [1]
    const float* __restrict__ u,          // [NS,B]
    float* __restrict__ out,              // [B]
    int B)
{
    const int wave = threadIdx.x >> 6;
    const int lane = threadIdx.x & 63;
    const int row  = blockIdx.x * ROWS_PER_BLOCK + wave;
    if (row >= B) return;

    const size_t base = (size_t)row * HDIM + (size_t)(lane << 2);

    const float4 vcx = *reinterpret_cast<const float4*>(cx    + base);
    const float4 vcb = *reinterpret_cast<const float4*>(cbarx + base);
    const float4 vdl = *reinterpret_cast<const float4*>(deltx + base);
    const float4 vox = *reinterpret_cast<const float4*>(ox    + base);
    const float4 vw  = *reinterpret_cast<const float4*>(W + (lane << 2));

    const float dur = duration[row];

    // all t-values up front (loads overlap)
    float t[NK];
    t[0] = dur;
#pragma unroll
    for (int s = 0; s < NS; ++s)
        t[s + 1] = u[(size_t)s * (size_t)B + (size_t)row] * dur;

    // per-row invariants
    float cb[4]  = {vcb.x, vcb.y, vcb.z, vcb.w};
    float dx[4]  = {vcx.x - vcb.x, vcx.y - vcb.y, vcx.z - vcb.z, vcx.w - vcb.w};
    float dln[4] = {-vdl.x, -vdl.y, -vdl.z, -vdl.w};
    float ow[4]  = {vox.x * vw.x, vox.y * vw.y, vox.z * vw.z, vox.w * vw.w};

    float acc[NK];
#pragma unroll
    for (int k = 0; k < NK; ++k) {
        const float tk = t[k];
        float a = 0.0f;
#pragma unroll
        for (int j = 0; j < 4; ++j) {
            float decay = __expf(dln[j] * tk);            // mul + mul(log2e) + v_exp
            float c_t   = fmaf(dx[j], decay, cb[j]);
            a = fmaf(ow[j], pade_tanh(c_t), a);
        }
        acc[k] = a;
    }

    // batched butterfly: issue all 11 shuffles per step so latencies overlap
#pragma unroll
    for (int off = 32; off > 0; off >>= 1) {
        float tmp[NK];
#pragma unroll
        for (int k = 0; k < NK; ++k) tmp[k] = __shfl_xor(acc[k], off, 64);
#pragma unroll
        for (int k = 0; k < NK; ++k) acc[k] += tmp[k];
    }

    // wave-parallel epilogue: lane k owns acc[k] (k=0..10)
    const float bb = bptr[0];
    float z = acc[0];
#pragma unroll
    for (int k = 1; k < NK; ++k) z = (lane == k) ? acc[k] : z;

    float sp   = softplus_f(z + bb);
    float nllv = -__logf(sp + EPS_F);
    const float scale = dur * (1.0f / (float)NS);

    float contrib = (lane == 0) ? nllv
                  : ((lane <= NS) ? sp * scale : 0.0f);
#pragma unroll
    for (int off = 32; off > 0; off >>= 1)
        contrib += __shfl_xor(contrib, off, 64);

    if (lane == 0) out[row] = contrib;
}

extern "C" void kernel_launch(void* const* d_in, const int* in_sizes, int n_in,
                              void* d_out, int out_size, void* d_ws, size_t ws_size,
                              hipStream_t stream) {
    const float* duration = (const float*)d_in[0];
    const float* cx       = (const float*)d_in[1];
    const float* cbarx    = (const float*)d_in[2];
    const float* deltx    = (const float*)d_in[3];
    const float* ox       = (const float*)d_in[4];
    const float* W        = (const float*)d_in[5];
    const float* b        = (const float*)d_in[6];
    const float* u        = (const float*)d_in[7];
    float* out            = (float*)d_out;

    const int B = in_sizes[0];           // 65536
    const int grid = (B + ROWS_PER_BLOCK - 1) / ROWS_PER_BLOCK;

    intensity_loss_kernel<<<grid, 256, 0, stream>>>(
        duration, cx, cbarx, deltx, ox, W, b, u, out, B);
}